// Round 7
// baseline (598.750 us; speedup 1.0000x reference)
//
#include <hip/hip_runtime.h>

// CTC batch cost (keras ctc_batch_cost), forward alpha recursion.
// B=128, T=512, C=1024, L=64, S=2L+1=129, blank = C-1.
//
// R7: the divergent gather y_pred[b,t,cls[lane]] was the wall (R4/R6
// evidence: ~0.04 lines/cy/CU on scattered loads; adding gather waves
// barely scaled it). Replace scatter with STREAMING:
//   Phase 1 ctc_extract (grid 128x8, 256 thr = 4 waves; 1024 blocks on all
//     256 CUs): each wave streams whole 4 KB class-rows with coalesced
//     float4 loads, stages them in a private 4 KB LDS scratch
//     (ds_write_b128, conflict-free), gathers the 64 label classes + blank
//     *inside LDS* (random b32 reads ~2 lanes/bank = free, m136), writes
//     log2-domain emissions to dense E[b][t][66] in d_ws. Rows t>=in_len
//     skipped. No barriers (per-wave scratch). ~208 MB streaming read.
//   Phase 2 ctc_rec (128 blocks x 1 wave): serial alpha recursion, one
//     coalesced 264 B E-row per step, depth-8 register ring. Exact same
//     math as R5/R6 (absmax == 0).
//
// Recursion: lane i owns extended states {2i,2i+1}; lane 63 also owns
// state 128. Cross-lane dep (state 2i-1 = prev lane's hi) via DPP
// wave_shr:1. Log2 domain (v_exp_f32/v_log_f32 are base-2 HW ops);
// ln alpha = log2 alpha * ln2 exactly, restored at the final loss.
//
// Inputs: d_in[0] y_true i32[B,L]; d_in[1] y_pred f32[B,T,C];
//         d_in[2] input_length i32[B,1]; d_in[3] label_length i32[B,1].
// Output: float [B,1].

constexpr int Tmax   = 512;
constexpr int Cch    = 1024;
constexpr int Lm     = 64;
constexpr int BLANKC = Cch - 1;
constexpr int ES     = 66;     // E row stride (64 labels + blank + pad)
constexpr int CH     = 64;     // timesteps per extract block
constexpr int PF2    = 8;      // recursion prefetch ring depth

#define NEGF (-1e9f)
#define EPSF (1e-7f)
#define LN2F (0.69314718055994530942f)

__device__ __forceinline__ float wave_shr1(float src, float fill) {
    int r = __builtin_amdgcn_update_dpp(__float_as_int(fill), __float_as_int(src),
                                        0x138, 0xf, 0xf, false);
    return __int_as_float(r);
}
__device__ __forceinline__ float lae2(float a, float b) {
    float m = fmaxf(a, b);
    return m + __builtin_log2f(__builtin_exp2f(a - m) + __builtin_exp2f(b - m));
}
__device__ __forceinline__ float lse3_2(float a, float b, float c) {
    float m = fmaxf(fmaxf(a, b), c);
    return m + __builtin_log2f(__builtin_exp2f(a - m) +
                               __builtin_exp2f(b - m) +
                               __builtin_exp2f(c - m));
}
__device__ __forceinline__ int clampi(int v, int lo, int hi) {
    return v < lo ? lo : (v > hi ? hi : v);
}

// ---------- Phase 1: streaming extraction (all 256 CUs) ----------
__global__ __launch_bounds__(256, 1) void ctc_extract(
    const int*   __restrict__ y_true,
    const float* __restrict__ y_pred,
    const int*   __restrict__ in_len,
    float*       __restrict__ E)
{
    const int b     = blockIdx.x;
    const int chunk = blockIdx.y;           // 0..7, covers t in [64c, 64c+64)
    const int wave  = threadIdx.x >> 6;     // 0..3
    const int lane  = threadIdx.x & 63;

    __shared__ float scr[4][Cch];           // 16 KB, per-wave private 4 KB

    const int Tb = clampi(in_len[b], 0, Tmax);
    const int nt = clampi(Tb - chunk * CH, 0, CH);   // rows to produce
    if (nt <= wave) return;                  // wave-uniform

    const int cls = y_true[b * Lm + lane];
    const float4* __restrict__ bv =
        (const float4*)(y_pred + ((size_t)b * Tmax + chunk * CH) * Cch);
    float4* __restrict__ s4 = (float4*)scr[wave];
    float*  __restrict__ sd = scr[wave];

    // wave handles local rows t = wave, wave+4, ... (< nt)
    float4 nxt[4];
#pragma unroll
    for (int k = 0; k < 4; ++k)
        nxt[k] = bv[(size_t)wave * 256 + k * 64 + lane];

    for (int t = wave; t < nt; t += 4) {
        float4 cur[4];
#pragma unroll
        for (int k = 0; k < 4; ++k) cur[k] = nxt[k];

        const int tn = t + 4;
        if (tn < nt) {
#pragma unroll
            for (int k = 0; k < 4; ++k)
                nxt[k] = bv[(size_t)tn * 256 + k * 64 + lane];
        }

        // stage row into private LDS scratch (conflict-free b128)
#pragma unroll
        for (int k = 0; k < 4; ++k) s4[k * 64 + lane] = cur[k];

        // in-LDS gather (random b32 ~2 lanes/bank; broadcast for blank)
        const float pc = sd[cls];
        const float pb = sd[BLANKC];

        const size_t e = ((size_t)b * Tmax + chunk * CH + t) * ES;
        E[e + lane] = __builtin_log2f(pc + EPSF);
        if (lane == 0) E[e + 64] = __builtin_log2f(pb + EPSF);
    }
}

// ---------- Phase 2: alpha recursion (latency chain) ----------
__global__ __launch_bounds__(64, 1) void ctc_rec(
    const int*   __restrict__ y_true,
    const int*   __restrict__ in_len,
    const int*   __restrict__ lab_len,
    const float* __restrict__ E,
    float*       __restrict__ out)
{
    const int b    = blockIdx.x;
    const int lane = threadIdx.x;

    const int cls = y_true[b * Lm + lane];
    const int Tb  = clampi(in_len[b], 0, Tmax);
    const int lb  = clampi(lab_len[b], 0, Lm);

    const int  cls_prev = __shfl_up(cls, 1, 64);
    const bool skip     = (lane >= 1) && (cls != cls_prev);

    const bool val_lo = (lane <= lb);        // state 2*lane
    const bool val_hi = (lane <  lb);        // state 2*lane+1
    const bool val_ex = (lb == Lm);          // state 128 (lane 63 only)

    float a_lo = (lane == 0) ? 0.f : NEGF;   // virtual alpha_{-1}
    float a_hi = NEGF;
    float a_ex = NEGF;

    const float* __restrict__ eb = E + (size_t)b * Tmax * ES;

    // coalesced prefetch ring over E rows (values already log2-domain)
    float pf_c[PF2], pf_b[PF2];
#pragma unroll
    for (int i = 0; i < PF2; ++i) {
        const float* row = eb + (size_t)i * ES;
        pf_c[i] = row[lane];
        pf_b[i] = row[64];
    }

    for (int t0 = 0; t0 < Tb; t0 += PF2) {
#pragma unroll
        for (int i = 0; i < PF2; ++i) {
            const int t = t0 + i;
            if (t >= Tb) break;              // Tb wave-uniform

            const float e_c = pf_c[i];
            const float e_b = pf_b[i];

            // refill slot for t+PF2 (clamped; rows >= Tb are poison but
            // never consumed)
            {
                int tp = t + PF2; int tr = tp < Tmax ? tp : Tmax - 1;
                const float* row = eb + (size_t)tr * ES;
                pf_c[i] = row[lane];
                pf_b[i] = row[64];
            }

            const float p_hi = wave_shr1(a_hi, NEGF);   // state 2i-1

            float n_lo = e_b + lae2(a_lo, p_hi);
            float n_hi = e_c + lse3_2(a_hi, a_lo, skip ? p_hi : NEGF);
            float n_ex = e_b + lae2(a_ex, a_hi);

            a_lo = val_lo ? n_lo : NEGF;
            a_hi = val_hi ? n_hi : NEGF;
            a_ex = val_ex ? n_ex : NEGF;
        }
    }

    const float a_end_blank = (lb == Lm) ? __shfl(a_ex, 63, 64)
                                         : __shfl(a_lo, lb, 64);
    const int   el_lane     = (lb >= 1) ? (lb - 1) : 0;
    const float a_end_label = (lb >= 1) ? __shfl(a_hi, el_lane, 64)
                                        : __shfl(a_lo, 0, 64);

    if (lane == 0) {
        out[b] = -LN2F * lae2(a_end_blank, a_end_label);
    }
}

// ---------- Fallback: fused single-kernel (R4, known-correct) ----------
__global__ __launch_bounds__(64, 1) void ctc_fused(
    const int*   __restrict__ y_true,
    const float* __restrict__ y_pred,
    const int*   __restrict__ in_len,
    const int*   __restrict__ lab_len,
    float*       __restrict__ out)
{
    const int b    = blockIdx.x;
    const int lane = threadIdx.x;
    const int cls  = y_true[b * Lm + lane];
    const int Tb   = clampi(in_len[b], 0, Tmax);
    const int lb   = clampi(lab_len[b], 0, Lm);

    const int  cls_prev = __shfl_up(cls, 1, 64);
    const bool skip     = (lane >= 1) && (cls != cls_prev);
    const bool val_lo = (lane <= lb);
    const bool val_hi = (lane <  lb);
    const bool val_ex = (lb == Lm);

    float a_lo = (lane == 0) ? 0.f : NEGF;
    float a_hi = NEGF, a_ex = NEGF;
    const float* __restrict__ base = y_pred + (size_t)b * Tmax * Cch;

    constexpr int PF = 8;
    float pf_c[PF], pf_b[PF];
#pragma unroll
    for (int i = 0; i < PF; ++i) {
        const float* row = base + (size_t)i * Cch;
        pf_c[i] = row[cls]; pf_b[i] = row[BLANKC];
    }
    for (int t0 = 0; t0 < Tb; t0 += PF) {
#pragma unroll
        for (int i = 0; i < PF; ++i) {
            const int t = t0 + i;
            if (t >= Tb) break;
            const float e_c = __builtin_log2f(pf_c[i] + EPSF);
            const float e_b = __builtin_log2f(pf_b[i] + EPSF);
            { int tp = t + PF; int tr = tp < Tmax ? tp : Tmax - 1;
              const float* row = base + (size_t)tr * Cch;
              pf_c[i] = row[cls]; pf_b[i] = row[BLANKC]; }
            const float p_hi = wave_shr1(a_hi, NEGF);
            float n_lo = e_b + lae2(a_lo, p_hi);
            float n_hi = e_c + lse3_2(a_hi, a_lo, skip ? p_hi : NEGF);
            float n_ex = e_b + lae2(a_ex, a_hi);
            a_lo = val_lo ? n_lo : NEGF;
            a_hi = val_hi ? n_hi : NEGF;
            a_ex = val_ex ? n_ex : NEGF;
        }
    }
    const float a_end_blank = (lb == Lm) ? __shfl(a_ex, 63, 64)
                                         : __shfl(a_lo, lb, 64);
    const int   el_lane     = (lb >= 1) ? (lb - 1) : 0;
    const float a_end_label = (lb >= 1) ? __shfl(a_hi, el_lane, 64)
                                        : __shfl(a_lo, 0, 64);
    if (lane == 0) out[b] = -LN2F * lae2(a_end_blank, a_end_label);
}

extern "C" void kernel_launch(void* const* d_in, const int* in_sizes, int n_in,
                              void* d_out, int out_size, void* d_ws, size_t ws_size,
                              hipStream_t stream) {
    const int*   y_true  = (const int*)  d_in[0];
    const float* y_pred  = (const float*)d_in[1];
    const int*   in_len  = (const int*)  d_in[2];
    const int*   lab_len = (const int*)  d_in[3];
    float*       out     = (float*)      d_out;

    const size_t need = (size_t)128 * Tmax * ES * sizeof(float);  // ~17.3 MB
    if (ws_size >= need) {
        float* E = (float*)d_ws;
        ctc_extract<<<dim3(128, Tmax / CH), dim3(256), 0, stream>>>(
            y_true, y_pred, in_len, E);
        ctc_rec<<<dim3(128), dim3(64), 0, stream>>>(
            y_true, in_len, lab_len, E, out);
    } else {
        ctc_fused<<<dim3(128), dim3(64), 0, stream>>>(
            y_true, y_pred, in_len, lab_len, out);
    }
}